// Round 7
// baseline (944.275 us; speedup 1.0000x reference)
//
#include <hip/hip_runtime.h>
#include <cstdint>

#define NN 100000
#define EE 3200000
#define SB_BITS 8
#define SB_NODES (1 << SB_BITS)                    // 256 nodes / superbucket
#define NSB ((NN + SB_NODES - 1) / SB_NODES)       // 391 superbuckets
#define CAP 9216                                   // max edges/sb in LDS (mean 8192, +11 sigma)
#define CH 4096                                    // edges per multisplit chunk
#define EPT (CH / 256)                             // 16 edges per thread

__device__ inline float4 add4(float4 a, float4 b) {
    return make_float4(a.x + b.x, a.y + b.y, a.z + b.z, a.w + b.w);
}

// pack two fp32 -> bf16x2 (RNE), lo in low half
__device__ inline unsigned pk_bf2(float lo, float hi) {
    unsigned a = __float_as_uint(lo);
    unsigned b = __float_as_uint(hi);
    a = (a + 0x7FFFu + ((a >> 16) & 1u)) >> 16;
    b = (b + 0x7FFFu + ((b >> 16) & 1u)) & 0xFFFF0000u;
    return a | b;
}

// ---------------- CSR build ----------------

// superbucket histogram (LDS-staged, flushed once per block)
__global__ void k_hist_sb(const int* __restrict__ dst, int* __restrict__ scnt) {
    __shared__ int h[NSB];
    for (int i = threadIdx.x; i < NSB; i += 256) h[i] = 0;
    __syncthreads();
    for (int e = blockIdx.x * 256 + threadIdx.x; e < EE; e += gridDim.x * 256)
        atomicAdd(&h[dst[e] >> SB_BITS], 1);
    __syncthreads();
    for (int i = threadIdx.x; i < NSB; i += 256) {
        int v = h[i];
        if (v) atomicAdd(&scnt[i], v);
    }
}

// single-block exclusive scan of NSB (<=512) superbucket counts
__global__ void k_scan_sb(const int* __restrict__ scnt,
                          int* __restrict__ sbptr, int* __restrict__ cursor) {
    __shared__ int sm[512];
    int i = threadIdx.x;   // 256 threads, each owns slots i and i+256
    int v0 = (i < NSB) ? scnt[i] : 0;
    int v1 = (i + 256 < NSB) ? scnt[i + 256] : 0;
    sm[i] = v0;
    sm[i + 256] = v1;
    __syncthreads();
    for (int o = 1; o < 512; o <<= 1) {
        int a0 = (i >= o) ? sm[i - o] : 0;
        int a1 = (i + 256 >= o) ? sm[i + 256 - o] : 0;
        __syncthreads();
        sm[i] += a0;
        sm[i + 256] += a1;
        __syncthreads();
    }
    if (i < NSB)       { sbptr[i]       = sm[i] - v0;       cursor[i]       = sm[i] - v0; }
    if (i + 256 < NSB) { sbptr[i + 256] = sm[i + 256] - v1; cursor[i + 256] = sm[i + 256] - v1; }
    if (i == 0) sbptr[NSB] = sm[511];   // == EE
}

// LDS multisplit: chunk of 4096 edges -> 391 bins, reorder in LDS,
// one global-cursor atomic per (bin,chunk), contiguous burst writes.
__global__ void k_split(const int* __restrict__ src, const int* __restrict__ dst,
                        int* __restrict__ cursor, int* __restrict__ out) {
    __shared__ int hist[512];     // padded to 512 for the scan
    __shared__ int lbase[NSB];
    __shared__ int gbase[NSB];
    __shared__ int buf[CH];
    __shared__ unsigned short keyb[CH];
    const int nchunks = (EE + CH - 1) / CH;
    for (int c = blockIdx.x; c < nchunks; c += gridDim.x) {
        int base = c * CH;
        int cnt = min(CH, EE - base);
        hist[threadIdx.x] = 0;
        hist[threadIdx.x + 256] = 0;
        __syncthreads();
        int words[EPT], ranks[EPT], keys[EPT];
        #pragma unroll
        for (int k = 0; k < EPT; ++k) {
            int idx = threadIdx.x + k * 256;
            if (idx < cnt) {
                int d = dst[base + idx];
                int s = src[base + idx];
                int key = d >> SB_BITS;
                words[k] = s | ((d & (SB_NODES - 1)) << 17);
                keys[k] = key;
                ranks[k] = atomicAdd(&hist[key], 1);
            } else keys[k] = -1;
        }
        __syncthreads();
        // 512-slot Hillis-Steele inclusive scan (thread owns i and i+256)
        int i = threadIdx.x;
        int v0 = hist[i], v1 = hist[i + 256];
        for (int o = 1; o < 512; o <<= 1) {
            int a0 = (i >= o) ? hist[i - o] : 0;
            int a1 = (i + 256 >= o) ? hist[i + 256 - o] : 0;
            __syncthreads();
            hist[i] += a0;
            hist[i + 256] += a1;
            __syncthreads();
        }
        if (i < NSB) {
            lbase[i] = hist[i] - v0;
            gbase[i] = (v0 > 0) ? atomicAdd(&cursor[i], v0) : 0;
        }
        if (i + 256 < NSB) {
            lbase[i + 256] = hist[i + 256] - v1;
            gbase[i + 256] = (v1 > 0) ? atomicAdd(&cursor[i + 256], v1) : 0;
        }
        __syncthreads();
        #pragma unroll
        for (int k = 0; k < EPT; ++k) {
            if (keys[k] >= 0) {
                int p = lbase[keys[k]] + ranks[k];
                buf[p] = words[k];
                keyb[p] = (unsigned short)keys[k];
            }
        }
        __syncthreads();
        for (int j = threadIdx.x; j < cnt; j += 256) {
            int kk = keyb[j];
            out[gbase[kk] + (j - lbase[kk])] = buf[j];
        }
        __syncthreads();
    }
}

// one block per superbucket: per-node counting sort via LDS staging,
// sorted result copied to global with fully sequential coalesced stores.
__global__ void k_sb_sort(const int* __restrict__ sbptr, const int* __restrict__ packed,
                          int* __restrict__ csr_src, int* __restrict__ rowptr) {
    __shared__ int hist[SB_NODES];   // -> exclusive offsets -> cursors
    __shared__ int lbuf[CAP];
    int b = blockIdx.x;
    int e0 = sbptr[b], e1 = sbptr[b + 1];
    int cnt = e1 - e0;
    hist[threadIdx.x] = 0;
    __syncthreads();
    for (int j = e0 + threadIdx.x; j < e1; j += 256)
        atomicAdd(&hist[(packed[j] >> 17) & (SB_NODES - 1)], 1);
    __syncthreads();
    // 256-slot inclusive scan, one slot per thread
    int i = threadIdx.x;
    int v = hist[i];
    for (int o = 1; o < 256; o <<= 1) {
        int a = (i >= o) ? hist[i - o] : 0;
        __syncthreads();
        hist[i] += a;
        __syncthreads();
    }
    int excl = hist[i] - v;
    int node = (b << SB_BITS) + i;
    if (node < NN) rowptr[node] = e0 + excl;
    hist[i] = excl;                   // becomes cursor
    if (b == 0 && i == 0) rowptr[NN] = EE;
    __syncthreads();
    if (cnt <= CAP) {
        for (int j = e0 + threadIdx.x; j < e1; j += 256) {
            int w = packed[j];
            int n = (w >> 17) & (SB_NODES - 1);
            int pos = atomicAdd(&hist[n], 1);
            lbuf[pos] = w & 0x1FFFF;
        }
        __syncthreads();
        for (int j = threadIdx.x; j < cnt; j += 256)
            csr_src[e0 + j] = lbuf[j];           // sequential coalesced
    } else {
        // overflow fallback (unreachable for this input): direct global scatter
        for (int j = e0 + threadIdx.x; j < e1; j += 256) {
            int w = packed[j];
            int n = (w >> 17) & (SB_NODES - 1);
            int pos = atomicAdd(&hist[n], 1);
            csr_src[e0 + pos] = w & 0x1FFFF;
        }
    }
}

// ---------------- GNN compute ----------------

// Weight-stationary LDS transform, register-budgeted (R16):
// R10-R14: s_load weight stream is the bottleneck (VALUBusy <=28%).
// R15 (weight-LDS, 8 nodes/lane) had the right mechanism but spilled
// (needed ~130 VGPR vs 85 cap -> WRITE_SIZE 220 MB of scratch).
// R16 budget: 4 nodes x 4 dims per lane: acc 16 + x ping-pong 32 + ptrs 8
// + weight 4 + misc ~15 = ~75 live < 102 cap (launch_bounds(256,5)).
//   Lane = slot*16+q. q in [0,16) owns 4 of the 64 concatenated outputs
//   (0-31 Wn dims -> t_bf, 32-63 Ws dims -> hout); slot owns 4 nodes.
//   Per k-step per wave: ONE ds_read_b128 (16 q-groups x 16B = 256B
//   distinct, 4-way slot broadcast -> 0 bank conflicts) vs 32 cy FMA.
//   Aggregate DS ~6.5us < 10.4us VALU floor -> weight delivery off the
//   critical path. x: 4-k-wide float4 tiles, 2-deep ping-pong, read once.
// 1563 blocks x 4 waves = 6252 waves; LDS 32KB -> 5 blocks/CU (~20 w/CU).
// fp32 FMA ascending-k per output == R11/R12 order -> identical numerics.
template <int DIN>
__global__ __launch_bounds__(256, 5) void k_transform(
        const float* __restrict__ h,
        const float* __restrict__ Wn,
        const float* __restrict__ Ws,
        const float* __restrict__ bn,
        unsigned* __restrict__ t_bf,
        float* __restrict__ hout) {
    __shared__ __align__(16) float wl[DIN * 64];   // [k][0:32)=Wn, [32:64)=Ws
    for (int i = threadIdx.x; i < DIN * 16; i += 256) {
        int k = i >> 4, c = i & 15;
        const float* sp = (c < 8) ? (Wn + k * 32 + c * 4) : (Ws + k * 32 + (c - 8) * 4);
        *(float4*)(&wl[k * 64 + c * 4]) = *(const float4*)sp;
    }
    __syncthreads();

    const int lane = threadIdx.x & 63;
    const int wv   = threadIdx.x >> 6;
    const int q    = lane & 15;          // 4-dim group of the 64 outputs
    const int slot = lane >> 4;          // 4-node group
    const int nbase = blockIdx.x * 64 + wv * 16 + slot * 4;
    const float* __restrict__ wq = wl + q * 4;

    const float* xp[4];
    #pragma unroll
    for (int r = 0; r < 4; ++r) {
        int n = nbase + r;
        xp[r] = h + (size_t)(n < NN ? n : NN - 1) * DIN;
    }

    float acc[4][4];                     // [node r][dim j], all idx static
    #pragma unroll
    for (int r = 0; r < 4; ++r)
        #pragma unroll
        for (int j = 0; j < 4; ++j) acc[r][j] = 0.f;

    float4 xa[4], xb[4];

    auto ldtile = [&](float4 (&dst)[4], int t) {
        #pragma unroll
        for (int r = 0; r < 4; ++r) dst[r] = *(const float4*)(xp[r] + t * 4);
    };
    auto comp4 = [&](const float4 (&xt)[4], int t) {
        #pragma unroll
        for (int kk = 0; kk < 4; ++kk) {
            float4 w4 = *(const float4*)(wq + (t * 4 + kk) * 64);   // ds_read_b128
            #pragma unroll
            for (int r = 0; r < 4; ++r) {
                float xv = (kk == 0) ? xt[r].x : (kk == 1) ? xt[r].y
                         : (kk == 2) ? xt[r].z : xt[r].w;
                acc[r][0] = fmaf(xv, w4.x, acc[r][0]);
                acc[r][1] = fmaf(xv, w4.y, acc[r][1]);
                acc[r][2] = fmaf(xv, w4.z, acc[r][2]);
                acc[r][3] = fmaf(xv, w4.w, acc[r][3]);
            }
        }
    };

    constexpr int T = DIN / 4;           // 32 or 8 (even)
    ldtile(xa, 0);
    for (int t = 0; t < T; t += 2) {
        ldtile(xb, t + 1);
        comp4(xa, t);
        if (t + 2 < T) ldtile(xa, t + 2);
        comp4(xb, t + 1);
    }

    // epilogue: q<8 -> bf16 neighbor words; q>=8 -> fp32 self + bias
    int bq = (q >= 8) ? (q - 8) : 0;
    float4 b4 = *(const float4*)(bn + bq * 4);
    #pragma unroll
    for (int r = 0; r < 4; ++r) {
        int node = nbase + r;
        if (node >= NN) continue;
        if (q < 8) {
            unsigned u0 = pk_bf2(acc[r][0], acc[r][1]);
            unsigned u1 = pk_bf2(acc[r][2], acc[r][3]);
            *(uint2*)(t_bf + (size_t)node * 16 + q * 2) = make_uint2(u0, u1);
        } else {
            *(float4*)(hout + (size_t)node * 32 + (q - 8) * 4) =
                make_float4(acc[r][0] + b4.x, acc[r][1] + b4.y,
                            acc[r][2] + b4.z, acc[r][3] + b4.w);
        }
    }
}

// 8 lanes per node, one bf16x4 (uint2, 8B) per lane = 64B/row = 1 line/edge.
// fp32 accumulate, 4-deep unroll: hout = relu(hout + seg_sum(t))
__global__ void k_aggregate(const int* __restrict__ rowptr,
                            const int* __restrict__ csr_src,
                            const uint2* __restrict__ t2,
                            float4* __restrict__ hout4) {
    int node = blockIdx.x * 32 + (threadIdx.x >> 3);
    int q = threadIdx.x & 7;
    if (node >= NN) return;
    int j = rowptr[node];
    int end = rowptr[node + 1];
    float4 a0 = make_float4(0.f, 0.f, 0.f, 0.f);
    float4 a1 = a0, a2 = a0, a3 = a0;
    for (; j + 4 <= end; j += 4) {
        int s0 = csr_src[j];
        int s1 = csr_src[j + 1];
        int s2 = csr_src[j + 2];
        int s3 = csr_src[j + 3];
        uint2 u0 = t2[s0 * 8 + q];
        uint2 u1 = t2[s1 * 8 + q];
        uint2 u2 = t2[s2 * 8 + q];
        uint2 u3 = t2[s3 * 8 + q];
        a0.x += __uint_as_float(u0.x << 16); a0.y += __uint_as_float(u0.x & 0xFFFF0000u);
        a0.z += __uint_as_float(u0.y << 16); a0.w += __uint_as_float(u0.y & 0xFFFF0000u);
        a1.x += __uint_as_float(u1.x << 16); a1.y += __uint_as_float(u1.x & 0xFFFF0000u);
        a1.z += __uint_as_float(u1.y << 16); a1.w += __uint_as_float(u1.y & 0xFFFF0000u);
        a2.x += __uint_as_float(u2.x << 16); a2.y += __uint_as_float(u2.x & 0xFFFF0000u);
        a2.z += __uint_as_float(u2.y << 16); a2.w += __uint_as_float(u2.y & 0xFFFF0000u);
        a3.x += __uint_as_float(u3.x << 16); a3.y += __uint_as_float(u3.x & 0xFFFF0000u);
        a3.z += __uint_as_float(u3.y << 16); a3.w += __uint_as_float(u3.y & 0xFFFF0000u);
    }
    for (; j < end; ++j) {
        uint2 u = t2[csr_src[j] * 8 + q];
        a0.x += __uint_as_float(u.x << 16); a0.y += __uint_as_float(u.x & 0xFFFF0000u);
        a0.z += __uint_as_float(u.y << 16); a0.w += __uint_as_float(u.y & 0xFFFF0000u);
    }
    float4 s = add4(add4(a0, a1), add4(a2, a3));
    int idx = node * 8 + q;
    float4 h = hout4[idx];
    h.x = fmaxf(h.x + s.x, 0.f);
    h.y = fmaxf(h.y + s.y, 0.f);
    h.z = fmaxf(h.z + s.z, 0.f);
    h.w = fmaxf(h.w + s.w, 0.f);
    hout4[idx] = h;
}

// concat(x,h1,h2,h3) @ fc_w + fc_b -> log_softmax
__global__ void k_final(const float* __restrict__ x,
                        const float* __restrict__ h1,
                        const float* __restrict__ h2,
                        const float* __restrict__ h3,
                        const float* __restrict__ fc_w,
                        const float* __restrict__ fc_b,
                        float* __restrict__ out) {
    __shared__ float Wl[224 * 10];
    __shared__ float bl[10];
    for (int i = threadIdx.x; i < 224 * 10; i += blockDim.x) Wl[i] = fc_w[i];
    if (threadIdx.x < 10) bl[threadIdx.x] = fc_b[threadIdx.x];
    __syncthreads();
    int n = blockIdx.x * blockDim.x + threadIdx.x;
    if (n >= NN) return;
    float acc[10];
    #pragma unroll
    for (int c = 0; c < 10; ++c) acc[c] = bl[c];
    const float* xr = x + (size_t)n * 128;
    for (int j = 0; j < 128; ++j) {
        float f = xr[j];
        #pragma unroll
        for (int c = 0; c < 10; ++c) acc[c] += f * Wl[j * 10 + c];
    }
    const float* hs[3] = {h1, h2, h3};
    for (int l = 0; l < 3; ++l) {
        const float* hr = hs[l] + (size_t)n * 32;
        for (int j = 0; j < 32; ++j) {
            float f = hr[j];
            #pragma unroll
            for (int c = 0; c < 10; ++c) acc[c] += f * Wl[(128 + l * 32 + j) * 10 + c];
        }
    }
    float m = acc[0];
    #pragma unroll
    for (int c = 1; c < 10; ++c) m = fmaxf(m, acc[c]);
    float s = 0.f;
    #pragma unroll
    for (int c = 0; c < 10; ++c) s += __expf(acc[c] - m);
    float ls = __logf(s);
    #pragma unroll
    for (int c = 0; c < 10; ++c) out[n * 10 + c] = acc[c] - m - ls;
}

extern "C" void kernel_launch(void* const* d_in, const int* in_sizes, int n_in,
                              void* d_out, int out_size, void* d_ws, size_t ws_size,
                              hipStream_t stream) {
    const float* x   = (const float*)d_in[0];
    const int*   src = (const int*)d_in[1];
    const int*   dst = (const int*)d_in[2];
    const float* Wn[3] = {(const float*)d_in[3], (const float*)d_in[6], (const float*)d_in[9]};
    const float* bn[3] = {(const float*)d_in[4], (const float*)d_in[7], (const float*)d_in[10]};
    const float* Ws[3] = {(const float*)d_in[5], (const float*)d_in[8], (const float*)d_in[11]};
    const float* fc_w = (const float*)d_in[12];
    const float* fc_b = (const float*)d_in[13];
    float* out = (float*)d_out;

    // workspace layout (packed aliases h3: packed is dead before h3 is written)
    char* w = (char*)d_ws;
    const size_t NF = (size_t)NN * 32;
    unsigned* t_bf = (unsigned*)w;              w += (size_t)NN * 16 * 4;  // 6.4 MB (bf16 t)
    float* h1  = (float*)w;                     w += NF * 4;
    float* h2  = (float*)w;                     w += NF * 4;
    float* h3  = (float*)w;                     w += NF * 4;
    int* csr_src = (int*)w;                     w += (size_t)EE * 4;  // 12.8 MB
    int* scnt   = (int*)w;                      w += (size_t)NSB * 4;
    int* sbptr  = (int*)w;                      w += (size_t)(NSB + 1) * 4;
    int* cursor = (int*)w;                      w += (size_t)NSB * 4;
    int* rowptr = (int*)w;                      w += (size_t)(NN + 1) * 4;
    int* packed = (int*)h3;   // temp, consumed by k_sb_sort before layers run

    // ---- CSR build: multisplit into 391 superbuckets + in-LDS counting sort ----
    hipMemsetAsync(scnt, 0, (size_t)NSB * 4, stream);
    k_hist_sb<<<512, 256, 0, stream>>>(dst, scnt);
    k_scan_sb<<<1, 256, 0, stream>>>(scnt, sbptr, cursor);
    k_split<<<512, 256, 0, stream>>>(src, dst, cursor, packed);
    k_sb_sort<<<NSB, 256, 0, stream>>>(sbptr, packed, csr_src, rowptr);

    // ---- layers ----
    const int tr_blocks = (NN + 63) / 64;                      // 1563, 64 nodes/block
    const int ag_blocks = (NN + 31) / 32;
    k_transform<128><<<tr_blocks, 256, 0, stream>>>(x, Wn[0], Ws[0], bn[0], t_bf, h1);
    k_aggregate<<<ag_blocks, 256, 0, stream>>>(rowptr, csr_src, (const uint2*)t_bf, (float4*)h1);
    k_transform<32><<<tr_blocks, 256, 0, stream>>>(h1, Wn[1], Ws[1], bn[1], t_bf, h2);
    k_aggregate<<<ag_blocks, 256, 0, stream>>>(rowptr, csr_src, (const uint2*)t_bf, (float4*)h2);
    k_transform<32><<<tr_blocks, 256, 0, stream>>>(h2, Wn[2], Ws[2], bn[2], t_bf, h3);
    k_aggregate<<<ag_blocks, 256, 0, stream>>>(rowptr, csr_src, (const uint2*)t_bf, (float4*)h3);
    k_final<<<(NN + 255) / 256, 256, 0, stream>>>(x, h1, h2, h3, fc_w, fc_b, out);
}

// Round 8
// 429.311 us; speedup vs baseline: 2.1995x; 2.1995x over previous
//
#include <hip/hip_runtime.h>
#include <cstdint>

#define NN 100000
#define EE 3200000
#define SB_BITS 8
#define SB_NODES (1 << SB_BITS)                    // 256 nodes / superbucket
#define NSB ((NN + SB_NODES - 1) / SB_NODES)       // 391 superbuckets
#define CAP 9216                                   // max edges/sb in LDS (mean 8192, +11 sigma)
#define CH 4096                                    // edges per multisplit chunk
#define EPT (CH / 256)                             // 16 edges per thread

__device__ inline float4 add4(float4 a, float4 b) {
    return make_float4(a.x + b.x, a.y + b.y, a.z + b.z, a.w + b.w);
}

// pack two fp32 -> bf16x2 (RNE), lo in low half
__device__ inline unsigned pk_bf2(float lo, float hi) {
    unsigned a = __float_as_uint(lo);
    unsigned b = __float_as_uint(hi);
    a = (a + 0x7FFFu + ((a >> 16) & 1u)) >> 16;
    b = (b + 0x7FFFu + ((b >> 16) & 1u)) & 0xFFFF0000u;
    return a | b;
}

// ---------------- CSR build ----------------

// superbucket histogram (LDS-staged, flushed once per block)
__global__ void k_hist_sb(const int* __restrict__ dst, int* __restrict__ scnt) {
    __shared__ int h[NSB];
    for (int i = threadIdx.x; i < NSB; i += 256) h[i] = 0;
    __syncthreads();
    for (int e = blockIdx.x * 256 + threadIdx.x; e < EE; e += gridDim.x * 256)
        atomicAdd(&h[dst[e] >> SB_BITS], 1);
    __syncthreads();
    for (int i = threadIdx.x; i < NSB; i += 256) {
        int v = h[i];
        if (v) atomicAdd(&scnt[i], v);
    }
}

// single-block exclusive scan of NSB (<=512) superbucket counts
__global__ void k_scan_sb(const int* __restrict__ scnt,
                          int* __restrict__ sbptr, int* __restrict__ cursor) {
    __shared__ int sm[512];
    int i = threadIdx.x;   // 256 threads, each owns slots i and i+256
    int v0 = (i < NSB) ? scnt[i] : 0;
    int v1 = (i + 256 < NSB) ? scnt[i + 256] : 0;
    sm[i] = v0;
    sm[i + 256] = v1;
    __syncthreads();
    for (int o = 1; o < 512; o <<= 1) {
        int a0 = (i >= o) ? sm[i - o] : 0;
        int a1 = (i + 256 >= o) ? sm[i + 256 - o] : 0;
        __syncthreads();
        sm[i] += a0;
        sm[i + 256] += a1;
        __syncthreads();
    }
    if (i < NSB)       { sbptr[i]       = sm[i] - v0;       cursor[i]       = sm[i] - v0; }
    if (i + 256 < NSB) { sbptr[i + 256] = sm[i + 256] - v1; cursor[i + 256] = sm[i + 256] - v1; }
    if (i == 0) sbptr[NSB] = sm[511];   // == EE
}

// LDS multisplit: chunk of 4096 edges -> 391 bins, reorder in LDS,
// one global-cursor atomic per (bin,chunk), contiguous burst writes.
__global__ void k_split(const int* __restrict__ src, const int* __restrict__ dst,
                        int* __restrict__ cursor, int* __restrict__ out) {
    __shared__ int hist[512];     // padded to 512 for the scan
    __shared__ int lbase[NSB];
    __shared__ int gbase[NSB];
    __shared__ int buf[CH];
    __shared__ unsigned short keyb[CH];
    const int nchunks = (EE + CH - 1) / CH;
    for (int c = blockIdx.x; c < nchunks; c += gridDim.x) {
        int base = c * CH;
        int cnt = min(CH, EE - base);
        hist[threadIdx.x] = 0;
        hist[threadIdx.x + 256] = 0;
        __syncthreads();
        int words[EPT], ranks[EPT], keys[EPT];
        #pragma unroll
        for (int k = 0; k < EPT; ++k) {
            int idx = threadIdx.x + k * 256;
            if (idx < cnt) {
                int d = dst[base + idx];
                int s = src[base + idx];
                int key = d >> SB_BITS;
                words[k] = s | ((d & (SB_NODES - 1)) << 17);
                keys[k] = key;
                ranks[k] = atomicAdd(&hist[key], 1);
            } else keys[k] = -1;
        }
        __syncthreads();
        // 512-slot Hillis-Steele inclusive scan (thread owns i and i+256)
        int i = threadIdx.x;
        int v0 = hist[i], v1 = hist[i + 256];
        for (int o = 1; o < 512; o <<= 1) {
            int a0 = (i >= o) ? hist[i - o] : 0;
            int a1 = (i + 256 >= o) ? hist[i + 256 - o] : 0;
            __syncthreads();
            hist[i] += a0;
            hist[i + 256] += a1;
            __syncthreads();
        }
        if (i < NSB) {
            lbase[i] = hist[i] - v0;
            gbase[i] = (v0 > 0) ? atomicAdd(&cursor[i], v0) : 0;
        }
        if (i + 256 < NSB) {
            lbase[i + 256] = hist[i + 256] - v1;
            gbase[i + 256] = (v1 > 0) ? atomicAdd(&cursor[i + 256], v1) : 0;
        }
        __syncthreads();
        #pragma unroll
        for (int k = 0; k < EPT; ++k) {
            if (keys[k] >= 0) {
                int p = lbase[keys[k]] + ranks[k];
                buf[p] = words[k];
                keyb[p] = (unsigned short)keys[k];
            }
        }
        __syncthreads();
        for (int j = threadIdx.x; j < cnt; j += 256) {
            int kk = keyb[j];
            out[gbase[kk] + (j - lbase[kk])] = buf[j];
        }
        __syncthreads();
    }
}

// one block per superbucket: per-node counting sort via LDS staging,
// sorted result copied to global with fully sequential coalesced stores.
__global__ void k_sb_sort(const int* __restrict__ sbptr, const int* __restrict__ packed,
                          int* __restrict__ csr_src, int* __restrict__ rowptr) {
    __shared__ int hist[SB_NODES];   // -> exclusive offsets -> cursors
    __shared__ int lbuf[CAP];
    int b = blockIdx.x;
    int e0 = sbptr[b], e1 = sbptr[b + 1];
    int cnt = e1 - e0;
    hist[threadIdx.x] = 0;
    __syncthreads();
    for (int j = e0 + threadIdx.x; j < e1; j += 256)
        atomicAdd(&hist[(packed[j] >> 17) & (SB_NODES - 1)], 1);
    __syncthreads();
    // 256-slot inclusive scan, one slot per thread
    int i = threadIdx.x;
    int v = hist[i];
    for (int o = 1; o < 256; o <<= 1) {
        int a = (i >= o) ? hist[i - o] : 0;
        __syncthreads();
        hist[i] += a;
        __syncthreads();
    }
    int excl = hist[i] - v;
    int node = (b << SB_BITS) + i;
    if (node < NN) rowptr[node] = e0 + excl;
    hist[i] = excl;                   // becomes cursor
    if (b == 0 && i == 0) rowptr[NN] = EE;
    __syncthreads();
    if (cnt <= CAP) {
        for (int j = e0 + threadIdx.x; j < e1; j += 256) {
            int w = packed[j];
            int n = (w >> 17) & (SB_NODES - 1);
            int pos = atomicAdd(&hist[n], 1);
            lbuf[pos] = w & 0x1FFFF;
        }
        __syncthreads();
        for (int j = threadIdx.x; j < cnt; j += 256)
            csr_src[e0 + j] = lbuf[j];           // sequential coalesced
    } else {
        // overflow fallback (unreachable for this input): direct global scatter
        for (int j = e0 + threadIdx.x; j < e1; j += 256) {
            int w = packed[j];
            int n = (w >> 17) & (SB_NODES - 1);
            int pos = atomicAdd(&hist[n], 1);
            csr_src[e0 + pos] = w & 0x1FFFF;
        }
    }
}

// ---------------- GNN compute ----------------

// Fused transform, half-width per block — R2 shape restored (R17):
// HISTORY (do not repeat): R1 full-width 64 accs -> spill/maxalloc (180us).
// R3 chunk-lambda rf[16] -> VGPR x2, regression. R5 quarter-split -> FETCH
// 734MB. R6/R7 weight-in-LDS with float4[ ] arrays through lambdas -> spilled
// (WRITE 220-337MB scratch) despite arithmetic saying it fits. ONLY this flat
// half-split shape (R2: 60us, 28 VGPR, zero scratch) survives allocation.
// R17 delta vs R2: 3-deep rolling prefetch (f0,f1,f2; covers ~768cy of the
// ~900cy HBM latency vs 512cy at 2-deep). No arrays, no lambdas.
// FMA order per output unchanged -> bit-identical results.
template <int DIN>
__global__ __launch_bounds__(64, 2) void k_transform(
        const float* __restrict__ h,
        const float* __restrict__ Wn,
        const float* __restrict__ Ws,
        const float* __restrict__ bn,
        unsigned* __restrict__ t_bf,
        float* __restrict__ hout) {
    const int half = blockIdx.x & 1;               // block-uniform
    const int d0 = half * 16;
    const int node = (blockIdx.x >> 1) * 64 + threadIdx.x;
    if (node >= NN) return;
    const float* __restrict__ hr = h + (size_t)node * DIN;
    float accn[16], accs[16];
    #pragma unroll
    for (int d = 0; d < 16; ++d) { accn[d] = 0.f; accs[d] = 0.f; }
    constexpr int NK4 = DIN / 4;
    float4 f0 = *(const float4*)(hr);
    float4 f1 = *(const float4*)(hr + 4);
    float4 f2 = *(const float4*)(hr + 8);          // NK4 >= 8 always (DIN>=32)
    #pragma unroll 2
    for (int k4 = 0; k4 < NK4; ++k4) {
        float4 cur = f0;
        f0 = f1;
        f1 = f2;
        if (k4 + 3 < NK4) f2 = *(const float4*)(hr + (k4 + 3) * 4);
        float fj[4] = {cur.x, cur.y, cur.z, cur.w};
        #pragma unroll
        for (int j = 0; j < 4; ++j) {
            float fv = fj[j];
            const float* __restrict__ wn = Wn + (k4 * 4 + j) * 32 + d0;  // uniform -> s_load
            const float* __restrict__ ws = Ws + (k4 * 4 + j) * 32 + d0;  // uniform -> s_load
            #pragma unroll
            for (int d = 0; d < 16; ++d) {
                accn[d] = fmaf(fv, wn[d], accn[d]);
                accs[d] = fmaf(fv, ws[d], accs[d]);
            }
        }
    }
    // neighbor path -> bf16 packed messages (this block's 16 dims = 8 words)
    unsigned tb[8];
    #pragma unroll
    for (int d = 0; d < 8; ++d) tb[d] = pk_bf2(accn[2 * d], accn[2 * d + 1]);
    unsigned* tp = t_bf + (size_t)node * 16 + half * 8;
    *(uint4*)(tp + 0) = make_uint4(tb[0], tb[1], tb[2], tb[3]);
    *(uint4*)(tp + 4) = make_uint4(tb[4], tb[5], tb[6], tb[7]);
    // self path -> fp32 hout = h@Ws + bn (this block's 16 dims)
    float* __restrict__ hp = hout + (size_t)node * 32 + d0;
    #pragma unroll
    for (int d = 0; d < 16; d += 4)
        *(float4*)(hp + d) = make_float4(accs[d] + bn[d0 + d], accs[d + 1] + bn[d0 + d + 1],
                                         accs[d + 2] + bn[d0 + d + 2], accs[d + 3] + bn[d0 + d + 3]);
}

// 8 lanes per node, one bf16x4 (uint2, 8B) per lane = 64B/row = 1 line/edge.
// fp32 accumulate, 4-deep unroll: hout = relu(hout + seg_sum(t))
__global__ void k_aggregate(const int* __restrict__ rowptr,
                            const int* __restrict__ csr_src,
                            const uint2* __restrict__ t2,
                            float4* __restrict__ hout4) {
    int node = blockIdx.x * 32 + (threadIdx.x >> 3);
    int q = threadIdx.x & 7;
    if (node >= NN) return;
    int j = rowptr[node];
    int end = rowptr[node + 1];
    float4 a0 = make_float4(0.f, 0.f, 0.f, 0.f);
    float4 a1 = a0, a2 = a0, a3 = a0;
    for (; j + 4 <= end; j += 4) {
        int s0 = csr_src[j];
        int s1 = csr_src[j + 1];
        int s2 = csr_src[j + 2];
        int s3 = csr_src[j + 3];
        uint2 u0 = t2[s0 * 8 + q];
        uint2 u1 = t2[s1 * 8 + q];
        uint2 u2 = t2[s2 * 8 + q];
        uint2 u3 = t2[s3 * 8 + q];
        a0.x += __uint_as_float(u0.x << 16); a0.y += __uint_as_float(u0.x & 0xFFFF0000u);
        a0.z += __uint_as_float(u0.y << 16); a0.w += __uint_as_float(u0.y & 0xFFFF0000u);
        a1.x += __uint_as_float(u1.x << 16); a1.y += __uint_as_float(u1.x & 0xFFFF0000u);
        a1.z += __uint_as_float(u1.y << 16); a1.w += __uint_as_float(u1.y & 0xFFFF0000u);
        a2.x += __uint_as_float(u2.x << 16); a2.y += __uint_as_float(u2.x & 0xFFFF0000u);
        a2.z += __uint_as_float(u2.y << 16); a2.w += __uint_as_float(u2.y & 0xFFFF0000u);
        a3.x += __uint_as_float(u3.x << 16); a3.y += __uint_as_float(u3.x & 0xFFFF0000u);
        a3.z += __uint_as_float(u3.y << 16); a3.w += __uint_as_float(u3.y & 0xFFFF0000u);
    }
    for (; j < end; ++j) {
        uint2 u = t2[csr_src[j] * 8 + q];
        a0.x += __uint_as_float(u.x << 16); a0.y += __uint_as_float(u.x & 0xFFFF0000u);
        a0.z += __uint_as_float(u.y << 16); a0.w += __uint_as_float(u.y & 0xFFFF0000u);
    }
    float4 s = add4(add4(a0, a1), add4(a2, a3));
    int idx = node * 8 + q;
    float4 h = hout4[idx];
    h.x = fmaxf(h.x + s.x, 0.f);
    h.y = fmaxf(h.y + s.y, 0.f);
    h.z = fmaxf(h.z + s.z, 0.f);
    h.w = fmaxf(h.w + s.w, 0.f);
    hout4[idx] = h;
}

// concat(x,h1,h2,h3) @ fc_w + fc_b -> log_softmax
// R17: row loads vectorized to float4 (was scalar; Common-mistake #2).
// FMA order per output (ascending j) unchanged -> bit-identical.
__global__ void k_final(const float* __restrict__ x,
                        const float* __restrict__ h1,
                        const float* __restrict__ h2,
                        const float* __restrict__ h3,
                        const float* __restrict__ fc_w,
                        const float* __restrict__ fc_b,
                        float* __restrict__ out) {
    __shared__ float Wl[224 * 10];
    __shared__ float bl[10];
    for (int i = threadIdx.x; i < 224 * 10; i += blockDim.x) Wl[i] = fc_w[i];
    if (threadIdx.x < 10) bl[threadIdx.x] = fc_b[threadIdx.x];
    __syncthreads();
    int n = blockIdx.x * blockDim.x + threadIdx.x;
    if (n >= NN) return;
    float acc[10];
    #pragma unroll
    for (int c = 0; c < 10; ++c) acc[c] = bl[c];
    const float4* xr4 = (const float4*)(x + (size_t)n * 128);
    for (int j4 = 0; j4 < 32; ++j4) {
        float4 f = xr4[j4];
        #pragma unroll
        for (int c = 0; c < 10; ++c) acc[c] += f.x * Wl[(j4 * 4 + 0) * 10 + c];
        #pragma unroll
        for (int c = 0; c < 10; ++c) acc[c] += f.y * Wl[(j4 * 4 + 1) * 10 + c];
        #pragma unroll
        for (int c = 0; c < 10; ++c) acc[c] += f.z * Wl[(j4 * 4 + 2) * 10 + c];
        #pragma unroll
        for (int c = 0; c < 10; ++c) acc[c] += f.w * Wl[(j4 * 4 + 3) * 10 + c];
    }
    const float* hs[3] = {h1, h2, h3};
    for (int l = 0; l < 3; ++l) {
        const float4* hr4 = (const float4*)(hs[l] + (size_t)n * 32);
        const int base = 128 + l * 32;
        for (int j4 = 0; j4 < 8; ++j4) {
            float4 f = hr4[j4];
            #pragma unroll
            for (int c = 0; c < 10; ++c) acc[c] += f.x * Wl[(base + j4 * 4 + 0) * 10 + c];
            #pragma unroll
            for (int c = 0; c < 10; ++c) acc[c] += f.y * Wl[(base + j4 * 4 + 1) * 10 + c];
            #pragma unroll
            for (int c = 0; c < 10; ++c) acc[c] += f.z * Wl[(base + j4 * 4 + 2) * 10 + c];
            #pragma unroll
            for (int c = 0; c < 10; ++c) acc[c] += f.w * Wl[(base + j4 * 4 + 3) * 10 + c];
        }
    }
    float m = acc[0];
    #pragma unroll
    for (int c = 1; c < 10; ++c) m = fmaxf(m, acc[c]);
    float s = 0.f;
    #pragma unroll
    for (int c = 0; c < 10; ++c) s += __expf(acc[c] - m);
    float ls = __logf(s);
    #pragma unroll
    for (int c = 0; c < 10; ++c) out[n * 10 + c] = acc[c] - m - ls;
}

extern "C" void kernel_launch(void* const* d_in, const int* in_sizes, int n_in,
                              void* d_out, int out_size, void* d_ws, size_t ws_size,
                              hipStream_t stream) {
    const float* x   = (const float*)d_in[0];
    const int*   src = (const int*)d_in[1];
    const int*   dst = (const int*)d_in[2];
    const float* Wn[3] = {(const float*)d_in[3], (const float*)d_in[6], (const float*)d_in[9]};
    const float* bn[3] = {(const float*)d_in[4], (const float*)d_in[7], (const float*)d_in[10]};
    const float* Ws[3] = {(const float*)d_in[5], (const float*)d_in[8], (const float*)d_in[11]};
    const float* fc_w = (const float*)d_in[12];
    const float* fc_b = (const float*)d_in[13];
    float* out = (float*)d_out;

    // workspace layout (packed aliases h3: packed is dead before h3 is written)
    char* w = (char*)d_ws;
    const size_t NF = (size_t)NN * 32;
    unsigned* t_bf = (unsigned*)w;              w += (size_t)NN * 16 * 4;  // 6.4 MB (bf16 t)
    float* h1  = (float*)w;                     w += NF * 4;
    float* h2  = (float*)w;                     w += NF * 4;
    float* h3  = (float*)w;                     w += NF * 4;
    int* csr_src = (int*)w;                     w += (size_t)EE * 4;  // 12.8 MB
    int* scnt   = (int*)w;                      w += (size_t)NSB * 4;
    int* sbptr  = (int*)w;                      w += (size_t)(NSB + 1) * 4;
    int* cursor = (int*)w;                      w += (size_t)NSB * 4;
    int* rowptr = (int*)w;                      w += (size_t)(NN + 1) * 4;
    int* packed = (int*)h3;   // temp, consumed by k_sb_sort before layers run

    // ---- CSR build: multisplit into 391 superbuckets + in-LDS counting sort ----
    hipMemsetAsync(scnt, 0, (size_t)NSB * 4, stream);
    k_hist_sb<<<512, 256, 0, stream>>>(dst, scnt);
    k_scan_sb<<<1, 256, 0, stream>>>(scnt, sbptr, cursor);
    k_split<<<512, 256, 0, stream>>>(src, dst, cursor, packed);
    k_sb_sort<<<NSB, 256, 0, stream>>>(sbptr, packed, csr_src, rowptr);

    // ---- layers ----
    const int tr_blocks = 2 * ((NN + 63) / 64);                // 3126, half per parity
    const int ag_blocks = (NN + 31) / 32;
    k_transform<128><<<tr_blocks, 64, 0, stream>>>(x, Wn[0], Ws[0], bn[0], t_bf, h1);
    k_aggregate<<<ag_blocks, 256, 0, stream>>>(rowptr, csr_src, (const uint2*)t_bf, (float4*)h1);
    k_transform<32><<<tr_blocks, 64, 0, stream>>>(h1, Wn[1], Ws[1], bn[1], t_bf, h2);
    k_aggregate<<<ag_blocks, 256, 0, stream>>>(rowptr, csr_src, (const uint2*)t_bf, (float4*)h2);
    k_transform<32><<<tr_blocks, 64, 0, stream>>>(h2, Wn[2], Ws[2], bn[2], t_bf, h3);
    k_aggregate<<<ag_blocks, 256, 0, stream>>>(rowptr, csr_src, (const uint2*)t_bf, (float4*)h3);
    k_final<<<(NN + 255) / 256, 256, 0, stream>>>(x, h1, h2, h3, fc_w, fc_b, out);
}